// Round 10
// baseline (3635.608 us; speedup 1.0000x reference)
//
#include <hip/hip_runtime.h>

// ---------------------------------------------------------------------------
// LSTM  T=2048, B=64, D=256, H=256  (fp32 in/out, bf16 MFMA compute)
//
//   G[t,b,c] = x[t,b,:] @ Wx[:,c] + bias[c]          (parallel GEMM, bf16 out)
//   per step: pre[c] = G[t,b,c] + h[t-1] @ Wh[:,c]   (persistent recurrent krn)
//   gates f,i,g,o -> c = f*c + i*g ; h = o*tanh(c)
//
// Round-10 = round-9 base (verified 3214us: round-1 structure + Tc=512 +
// packed-bf16 G) + IN-LANE GATE FUSION WITH COALESCED PUBLISH:
//   * MFMA operands swapped: acc = mfma(aw, af, acc) with WREC A-frags
//     (gate-interleaved M rows, VERIFIED CORRECT in round 3 — it passed).
//     Lane's 4 acc regs = 4 gates of one (batch bl=l&15, col colw).
//   * combine fully in-lane, transcendentals BEFORE bar2 (overlap wave skew);
//     gbuf + its read-back DELETED. Post-bar2 path = LDS h read + publish.
//   * h re-coalesced through hout[16][34] fp32 LDS tile: publish/out threads
//     (b_, j_) use the EXACT round-1 coalesced store pattern (round-3 lesson:
//     scattered publish = write amp + multi-wave poll windows, never again).
//   * G staged through gsm64[16][33] (u64 rows, padded: conflict-free b64
//     reads): coalesced 8B G2 load pre-poll (hidden, round-9 verified),
//     pinned post-poll via asm "+v"(gv), 4x ds_write_b16 (2-way, free).
//   * bar3 unnecessary here: staging(t+1) touches hsm/gsm only; every wave
//     drains its LDS reads (lgkmcnt(0)) at each barrier ARRIVAL, so passing
//     bar2(t) proves all hsm/gsm(t) reads done; hout(t+1) writes happen after
//     bar1(t+1), which requires all hout(t) reads drained. 2 barriers/step.
//
// Exchange protocol UNCHANGED (round-1 verified): self-describing u32 words
//   word = (tag << 16) | bf16(h), tag = t+1; agent-scope UC (sc1) path only.
// Poll = 2 concurrent global_load_dwordx4 sc1 + vmcnt(0), retry on tag miss;
// "=&v" early-clobber + sched_barrier(0) after waits. Per-u32 tags make 16B
// tearing harmless. Termination: parity double buffer. Overwrite safety:
// publishing tag t+1 (post-bar2) requires having observed tag t from ALL
// slices at poll(t) => all WGs published t => all consumed t-1.
// hbuf MUST be 128 KB. Mode-A (L2/sc0 exchange) abandoned (stale clean lines).
// Round-6 lesson (FAILED): asm-held async register prefetch is not spill-safe.
// Round-8 lesson: HIP predefines ushort4 -> use ushort4v.
// ---------------------------------------------------------------------------

typedef __attribute__((ext_vector_type(8))) short short8;
typedef __attribute__((ext_vector_type(4))) float float4v;
typedef __attribute__((ext_vector_type(4))) unsigned int uint4v;
typedef __attribute__((ext_vector_type(4))) unsigned short ushort4v;

#define TT   2048
#define BB   64
#define HH   256
#define TBH  ((size_t)33554432)   // T*B*H
#define BH   ((size_t)16384)      // B*H

// workspace layout (bytes)
#define WS_WT    0u          // 1 MB    bf16 WT[1024][512]  (x-part used by gemm)
#define WS_BVEC  1048576u    // 4 KB    fp32 bias[1024]
#define WS_HBUF  1052672u    // 128 KB  u32 hbuf[4][2][16][256] tagged cols
#define WS_CST   1183744u    // 64 KB   fp32 cstate[64][256]
#define WS_WREC  1249280u    // 512 KB  bf16 WREC: recurrent W, MFMA-frag order
#define WS_G     1773568u    // Tc*64*1024*2  bf16 G2 [R/4][1024][4]

__device__ inline unsigned short f2bf(float x) {
    unsigned u = __float_as_uint(x);
    unsigned r = (u + 0x7FFFu + ((u >> 16) & 1u)) >> 16;
    return (unsigned short)r;
}
__device__ inline float bf2f(unsigned short x) {
    return __uint_as_float((unsigned)x << 16);
}
__device__ inline float sigmoidf_(float x) { return 1.0f / (1.0f + __expf(-x)); }
__device__ inline float tanhf_(float x) {
    float e = __expf(-2.0f * fabsf(x));
    float t = (1.0f - e) / (1.0f + e);
    return copysignf(t, x);
}

// LDS-only workgroup barrier: orders ds ops without draining vmcnt
// (publish/out store-acks + G loads stay in flight across the barrier).
__device__ inline void bar_lds() {
    asm volatile("s_waitcnt lgkmcnt(0)\n\ts_barrier" ::: "memory");
}

// ---------------------------------------------------------------------------
// Prep: WT[c][k] = W_gate(c/256)[k][c%256]  (bf16, k in [0,512)), bvec[c]=bias
// ---------------------------------------------------------------------------
__global__ void k_prep_w(const float* __restrict__ Wf, const float* __restrict__ Wi,
                         const float* __restrict__ Wg, const float* __restrict__ Wo,
                         const float* __restrict__ bf_, const float* __restrict__ bi_,
                         const float* __restrict__ bg_, const float* __restrict__ bo_,
                         unsigned short* __restrict__ WT, float* __restrict__ bvec)
{
    int c = blockIdx.x;            // 0..1023
    int gate = c >> 8, j = c & 255;
    const float* W  = (gate == 0) ? Wf : (gate == 1) ? Wi : (gate == 2) ? Wg : Wo;
    const float* bb = (gate == 0) ? bf_ : (gate == 1) ? bi_ : (gate == 2) ? bg_ : bo_;
    for (int k = threadIdx.x; k < 512; k += 256)
        WT[(size_t)c * 512 + k] = f2bf(W[(size_t)k * 256 + j]);
    if (threadIdx.x == 0) bvec[c] = bb[j];
}

// ---------------------------------------------------------------------------
// Prep recurrent weights in MFMA A-fragment order, gate-interleaved M-rows.
// (VERBATIM from round 3 — correctness-verified there.)
// Block (s*8+wv): slice s (0..7), wave wv (0..7). Fragment for (kk, lane l):
//   m = l&15 -> cidx=(l&15)>>2, gate=l&3;  col = s*32 + wv*4 + cidx
//   k elems = 256 + kk*32 + (l>>4)*8 + e   (recurrent rows of W)
// Layout: WREC[(s*8+wv)*4096 + kk*512 + l*8 + e]  (u16)
// ---------------------------------------------------------------------------
__global__ void k_prep_wrec(const float* __restrict__ Wf, const float* __restrict__ Wi,
                            const float* __restrict__ Wg, const float* __restrict__ Wo,
                            unsigned short* __restrict__ WREC)
{
    int bid = blockIdx.x;          // 0..63
    int slice = bid >> 3, wv = bid & 7;
    for (int idx = threadIdx.x; idx < 512; idx += 256) {
        int kk = idx >> 6, l = idx & 63;
        int col  = slice * 32 + wv * 4 + ((l & 15) >> 2);
        int gate = l & 3;
        const float* W = (gate == 0) ? Wf : (gate == 1) ? Wi : (gate == 2) ? Wg : Wo;
        unsigned short* dst = WREC + (size_t)bid * 4096 + kk * 512 + l * 8;
#pragma unroll
        for (int e = 0; e < 8; ++e) {
            int k = 256 + kk * 32 + (l >> 4) * 8 + e;
            dst[e] = f2bf(W[(size_t)k * 256 + col]);
        }
    }
}

__global__ void k_zero(unsigned int* __restrict__ hbuf, float* __restrict__ cst)
{
    int tid = blockIdx.x * blockDim.x + threadIdx.x;
    int nt = gridDim.x * blockDim.x;
    for (int i = tid; i < 32768; i += nt) hbuf[i] = 0u;  // 128 KB, tag 0 = h_{-1}=0
    for (int i = tid; i < 16384; i += nt) cst[i] = 0.f;  // 64 KB
}

// ---------------------------------------------------------------------------
// Phase 1: G2[r>>2][c][r&3] = bf16( sum_k X[r][k]*WT[c][k] + bvec[c] )
// 128x128 tile, 4 waves, BK=64, XOR-swizzled LDS, fp32->bf16 on the fly.
// ---------------------------------------------------------------------------
__global__ __launch_bounds__(256) void gemm_xw(
    const float* __restrict__ X,           // chunk base [R][256] fp32
    const unsigned short* __restrict__ WT, // [1024][512] bf16
    const float* __restrict__ bvec,
    unsigned short* __restrict__ G2)       // [R/4][1024][4] bf16 packed
{
    int col0 = blockIdx.x * 128;
    int row0 = blockIdx.y * 128;
    int tid = threadIdx.x, l = tid & 63, w = tid >> 6;
    int wr = w >> 1, wc = w & 1;

    __shared__ __align__(16) unsigned char asm_[16384];
    __shared__ __align__(16) unsigned char bsm_[16384];

    float4v acc[4][4];
#pragma unroll
    for (int i = 0; i < 4; ++i)
#pragma unroll
        for (int j = 0; j < 4; ++j) { acc[i][j][0] = 0.f; acc[i][j][1] = 0.f; acc[i][j][2] = 0.f; acc[i][j][3] = 0.f; }

    for (int kt = 0; kt < 4; ++kt) {
        // stage A (fp32 -> bf16): 128 rows x 64 k
        {
            int r = tid >> 1, seg = tid & 1;
            const float* src = X + (size_t)(row0 + r) * 256 + kt * 64 + seg * 32;
            short8 tmp[4];
#pragma unroll
            for (int v = 0; v < 4; ++v)
#pragma unroll
                for (int e = 0; e < 8; ++e) tmp[v][e] = (short)f2bf(src[v * 8 + e]);
            unsigned char* dst = asm_ + r * 128;
            int base = seg * 64, swz = (r & 7) << 4;
#pragma unroll
            for (int v = 0; v < 4; ++v)
                *(short8*)(dst + ((base + 16 * v) ^ swz)) = tmp[v];
        }
        // stage B (bf16 copy): 128 cols x 64 k
        {
            int c_ = tid >> 1, seg = tid & 1;
            const unsigned char* src = (const unsigned char*)WT + (size_t)(col0 + c_) * 1024 + kt * 128 + seg * 64;
            unsigned char* dst = bsm_ + c_ * 128;
            int base = seg * 64, swz = (c_ & 7) << 4;
#pragma unroll
            for (int v = 0; v < 4; ++v)
                *(short8*)(dst + ((base + 16 * v) ^ swz)) = *(const short8*)(src + 16 * v);
        }
        __syncthreads();
#pragma unroll
        for (int km = 0; km < 2; ++km) {
            short8 af[4], bfr[4];
            int kb = 16 * (l >> 4) + 64 * km, swz = (l & 7) << 4;
#pragma unroll
            for (int i = 0; i < 4; ++i)
                af[i] = *(const short8*)(asm_ + (wr * 64 + i * 16 + (l & 15)) * 128 + (kb ^ swz));
#pragma unroll
            for (int j = 0; j < 4; ++j)
                bfr[j] = *(const short8*)(bsm_ + (wc * 64 + j * 16 + (l & 15)) * 128 + (kb ^ swz));
#pragma unroll
            for (int i = 0; i < 4; ++i)
#pragma unroll
                for (int j = 0; j < 4; ++j)
                    acc[i][j] = __builtin_amdgcn_mfma_f32_16x16x32_bf16(af[i], bfr[j], acc[i][j], 0, 0, 0);
        }
        __syncthreads();
    }
    // epilogue: + bias, pack 4 row-values to bf16, one 8B store each
#pragma unroll
    for (int j = 0; j < 4; ++j) {
        int col = col0 + wc * 64 + j * 16 + (l & 15);
        float bias = bvec[col];
#pragma unroll
        for (int i = 0; i < 4; ++i) {
            int row = row0 + wr * 64 + i * 16 + (l >> 4) * 4;   // row % 4 == 0
            ushort4v v;
            v[0] = f2bf(acc[i][j][0] + bias);
            v[1] = f2bf(acc[i][j][1] + bias);
            v[2] = f2bf(acc[i][j][2] + bias);
            v[3] = f2bf(acc[i][j][3] + bias);
            *(ushort4v*)(G2 + ((size_t)(row >> 2) * 1024 + col) * 4) = v;
        }
    }
}

// ---------------------------------------------------------------------------
// Phase 2: persistent recurrent kernel for a chunk of Tc steps.
// Grid 64 blocks x 512 thr; g = wg&7 (>=4 -> exit), s = wg>>3.
// Wave w (0..7): 4 h-cols (s*32 + w*4 .. +4) x 4 gates, K=256, in-lane fused.
// Lane l: batch bl = l&15, col colw = s*32 + w*4 + (l>>4); acc regs = 4 gates.
// ---------------------------------------------------------------------------
__global__ __launch_bounds__(512) void lstm_rec(
    const unsigned short* __restrict__ G2,  // [Tc*16][1024][4] bf16 packed
    const unsigned short* __restrict__ WREC,// frag-ordered recurrent W
    float* __restrict__ out,
    unsigned int* __restrict__ hbuf,        // [4][2][16][256] tagged cols
    float* __restrict__ cstate,             // [64][256] fp32
    int t0, int Tc)
{
    int wg = blockIdx.x;
    int g = wg & 7;
    if (g >= 4) return;
    int s = wg >> 3;                  // 0..7

    int tid = threadIdx.x, l = tid & 63, w = tid >> 6;
    int bl = l & 15, cw = l >> 4;
    int colw = s * 32 + w * 4 + cw;

    __shared__ __align__(16) unsigned char hsm[8192];   // h tile [16][256] bf16, swizzled
    __shared__ unsigned long long gsm64[16][33];        // G tile [batch][hcol] 4x bf16 gates (padded)
    __shared__ float hout[16][34];                      // h fp32 [batch][hcol] (padded)

    // recurrent weights -> registers (A-frags, gate-interleaved M rows)
    short8 aw[8];
    {
        const unsigned short* wp_ = WREC + (size_t)(s * 8 + w) * 4096 + l * 8;
#pragma unroll
        for (int kk = 0; kk < 8; ++kk) aw[kk] = *(const short8*)(wp_ + kk * 512);
    }

    // per-lane c state for (bl, colw)
    float creg = cstate[(size_t)(g * 16 + bl) * 256 + colw];

    // poll/staging mapping: row srow (0..15), 8-col window sblk (0..31)
    int srow = tid >> 5, sblk = tid & 31;
    unsigned char* hsm_dst = hsm + srow * 512 + ((sblk * 16) ^ ((srow & 7) << 4));

    // G staging map: hcol (0..31), gate (0..3), batch-quad gq (0..3)
    int ghcol = tid & 31, ggate = (tid >> 5) & 3, gq = tid >> 7;

    // publish map (round-1 coalesced): row b_ (0..15), col j_ (0..31)
    int b_ = tid >> 5, j_ = tid & 31;

    for (int tl = 0; tl < Tc; ++tl) {
        int tg = t0 + tl;
        int par = tg & 1, rpar = par ^ 1;

        // G preload: ONE 8B packed load (4 batches of one gate-col), issued
        // before the poll; drained by the poll's vmcnt(0) (round-9 verified).
        ushort4v gv;
        {
            const unsigned short* Gp = G2 +
                ((size_t)(tl * 16 + g * 4 + gq) * 1024 + ggate * 256 + s * 32 + ghcol) * 4;
            gv = *(const ushort4v*)Gp;
        }
        // spin-read h_{tg-1}: 2 CONCURRENT dwordx4 sc1 (agent UC) loads,
        // one vmcnt(0) (also drains the G load + prior store-acks, all
        // overlapped with the load RTT); retry both on any tag miss.
        {
            const unsigned int* wp = hbuf + ((size_t)((g * 2 + rpar) * 16) + srow) * 256 + sblk * 8;
            unsigned want = (unsigned)tg;
            short8 hv;
            uint4v w0, w1;
            for (;;) {
                asm volatile("global_load_dwordx4 %0, %2, off sc1\n\t"
                             "global_load_dwordx4 %1, %3, off sc1\n\t"
                             "s_waitcnt vmcnt(0)"
                             : "=&v"(w0), "=&v"(w1)
                             : "v"(wp), "v"(wp + 4) : "memory");
                __builtin_amdgcn_sched_barrier(0);
                if (((w0[0] >> 16) == want) & ((w0[1] >> 16) == want) &
                    ((w0[2] >> 16) == want) & ((w0[3] >> 16) == want) &
                    ((w1[0] >> 16) == want) & ((w1[1] >> 16) == want) &
                    ((w1[2] >> 16) == want) & ((w1[3] >> 16) == want)) break;
            }
            hv[0] = (short)(w0[0] & 0xffffu);
            hv[1] = (short)(w0[1] & 0xffffu);
            hv[2] = (short)(w0[2] & 0xffffu);
            hv[3] = (short)(w0[3] & 0xffffu);
            hv[4] = (short)(w1[0] & 0xffffu);
            hv[5] = (short)(w1[1] & 0xffffu);
            hv[6] = (short)(w1[2] & 0xffffu);
            hv[7] = (short)(w1[3] & 0xffffu);
            *(short8*)hsm_dst = hv;
        }
        // stage G into gsm (gv valid after the poll's vmcnt(0); pin so the
        // compiler can't hoist the use above it). 4x ds_write_b16, 2-way free.
        asm volatile("" : "+v"(gv));
#pragma unroll
        for (int k = 0; k < 4; ++k)
            *(unsigned short*)((unsigned char*)&gsm64[gq * 4 + k][ghcol] + ggate * 2) = (unsigned short)gv[k];
        bar_lds();   // bar1: hsm + gsm visible
        // pre = G + Wh(frag) @ h(frag): af reads identical to round-1's
        float4v acc, acc1;
        {
            unsigned long long gq64 = gsm64[bl][w * 4 + cw];
            acc[0] = bf2f((unsigned short)(gq64));
            acc[1] = bf2f((unsigned short)(gq64 >> 16));
            acc[2] = bf2f((unsigned short)(gq64 >> 32));
            acc[3] = bf2f((unsigned short)(gq64 >> 48));
            const unsigned char* ap = hsm + bl * 512;
            int kb0 = 16 * (l >> 4), swz = (bl & 7) << 4;
            short8 af[8];
#pragma unroll
            for (int kk = 0; kk < 8; ++kk) af[kk] = *(const short8*)(ap + ((kb0 + 64 * kk) ^ swz));
            acc1[0] = 0.f; acc1[1] = 0.f; acc1[2] = 0.f; acc1[3] = 0.f;
#pragma unroll
            for (int kk = 0; kk < 4; ++kk) {
                acc  = __builtin_amdgcn_mfma_f32_16x16x32_bf16(aw[kk],     af[kk],     acc,  0, 0, 0);
                acc1 = __builtin_amdgcn_mfma_f32_16x16x32_bf16(aw[kk + 4], af[kk + 4], acc1, 0, 0, 0);
            }
            acc[0] += acc1[0]; acc[1] += acc1[1]; acc[2] += acc1[2]; acc[3] += acc1[3];
        }
        // combine IN-LANE (before bar2): acc = {f,i,g,o} of (bl, colw)
        {
            float f  = sigmoidf_(acc[0]);
            float ii = sigmoidf_(acc[1]);
            float gg = tanhf_(acc[2]);
            float o  = sigmoidf_(acc[3]);
            creg = f * creg + ii * gg;
            float h = o * tanhf_(creg);
            hout[bl][w * 4 + cw] = h;
            if (tg == TT - 1)
                out[TBH + BH + (size_t)(g * 16 + bl) * 256 + colw] = creg;  // final c (once)
        }
        bar_lds();   // bar2: hout visible; all waves' hsm/gsm reads retired
        // publish/out: round-1 coalesced pattern (32 lanes = one 128B line)
        {
            float h32 = hout[b_][j_];
            unsigned word = ((unsigned)(tg + 1) << 16) | (unsigned)f2bf(h32);
            __hip_atomic_store(hbuf + ((size_t)((g * 2 + par) * 16) + b_) * 256 + s * 32 + j_,
                               word, __ATOMIC_RELAXED, __HIP_MEMORY_SCOPE_AGENT);
            size_t orow = (size_t)tg * 64 + g * 16 + b_;
            out[orow * 256 + s * 32 + j_] = h32;
            if (tg == TT - 1)
                out[TBH + (size_t)(g * 16 + b_) * 256 + s * 32 + j_] = h32;  // final h (once)
        }
        // no bar3: staging(t+1) touches hsm/gsm only — all their (t) reads
        // drained at each wave's bar2 arrival; hout(t+1) writes happen after
        // bar1(t+1), which requires all hout(t) reads drained at arrival.
    }
    cstate[(size_t)(g * 16 + bl) * 256 + colw] = creg;
}

// ---------------------------------------------------------------------------
extern "C" void kernel_launch(void* const* d_in, const int* in_sizes, int n_in,
                              void* d_out, int out_size, void* d_ws, size_t ws_size,
                              hipStream_t stream)
{
    (void)in_sizes; (void)n_in; (void)out_size;
    const float* X   = (const float*)d_in[0];
    const float* Wf  = (const float*)d_in[1];
    const float* bf_ = (const float*)d_in[2];
    const float* Wi  = (const float*)d_in[3];
    const float* bi_ = (const float*)d_in[4];
    const float* Wg  = (const float*)d_in[5];
    const float* bg_ = (const float*)d_in[6];
    const float* Wo  = (const float*)d_in[7];
    const float* bo_ = (const float*)d_in[8];
    float* out = (float*)d_out;
    unsigned char* ws = (unsigned char*)d_ws;

    unsigned short* WT   = (unsigned short*)(ws + WS_WT);
    float*          bvec = (float*)(ws + WS_BVEC);
    unsigned int*   hbuf = (unsigned int*)(ws + WS_HBUF);
    float*          cst  = (float*)(ws + WS_CST);
    unsigned short* WREC = (unsigned short*)(ws + WS_WREC);
    unsigned short* G2   = (unsigned short*)(ws + WS_G);

    // Tc capped at 512: bf16 G chunk = 64 MB, L3-resident between gemm
    // (writer) and lstm_rec (reader).
    size_t avail = ws_size > WS_G ? ws_size - WS_G : 0;
    int Tc = 8;
    const int cands[7] = {512, 256, 128, 64, 32, 16, 8};
    for (int i = 0; i < 7; ++i) {
        if ((size_t)cands[i] * 64 * 1024 * 2 <= avail) { Tc = cands[i]; break; }
    }

    k_prep_w<<<1024, 256, 0, stream>>>(Wf, Wi, Wg, Wo, bf_, bi_, bg_, bo_, WT, bvec);
    k_prep_wrec<<<64, 256, 0, stream>>>(Wf, Wi, Wg, Wo, WREC);
    k_zero<<<64, 256, 0, stream>>>(hbuf, cst);

    for (int t0 = 0; t0 < TT; t0 += Tc) {
        int R = Tc * 64;
        gemm_xw<<<dim3(8, R / 128), 256, 0, stream>>>(X + (size_t)t0 * 64 * 256, WT, bvec, G2);
        lstm_rec<<<64, 512, 0, stream>>>(G2, WREC, out, hbuf, cst, t0, Tc);
    }
}

// Round 11
// 3212.280 us; speedup vs baseline: 1.1318x; 1.1318x over previous
//
#include <hip/hip_runtime.h>

// ---------------------------------------------------------------------------
// LSTM  T=2048, B=64, D=256, H=256  (fp32 in/out, bf16 MFMA compute)
//
//   G[t,b,c] = x[t,b,:] @ Wx[:,c] + bias[c]          (parallel GEMM)
//   per step: pre[c] = G[t,b,c] + h[t-1] @ Wh[:,c]   (persistent recurrent krn)
//   gates f,i,g,o -> c = f*c + i*g ; h = o*tanh(c)
//
// Round-11 = round-9 (verified 3214us: round-1 structure + Tc=512 + packed
// bf16 G) with ONE change: __launch_bounds__(512, 1) on lstm_rec.
// Rationale: grid = 64 WGs on 256 CUs -> 1 WG/CU, occupancy is IRRELEVANT,
// yet the compiler allocated only 40 VGPRs (rounds 1/9/10 all 40-48) — too
// few to keep bw[8] (32 VGPRs of recurrent weights) resident. It has been
// REMATERIALIZING the 8 weight dwordx4 loads from L2 inside every step's
// MFMA section (~200-400cy partially exposed on the serial chain). min-waves
// =1 lifts the VGPR cap so the loop-invariant weights stay in registers.
// Validating counter: VGPR_Count must jump 40 -> >=80. Plain loads only —
// spill-safe by construction (round-6 lesson: no asm-held async regs).
// Round-10 lesson (REGRESSED +106us): in-lane gate fusion at VGPR=40 forced
// aw remat + extra LDS staging; reverted.
//
// Recurrent kernel: 4 batch-groups (M=16) x 8 column-slice WGs (128 cols each).
// h exchange FENCE-FREE via self-describing u32 words:
//   word = (tag << 16) | bf16(h),  tag = t+1  (tags <= 2048 < 2^16)
// All exchange traffic uses the agent-scope UC path (bypasses per-XCD L2s ->
// correct for ANY workgroup placement; no L2-residency staleness, no fences).
// Poll = 2 CONCURRENT global_load_dwordx4 sc1 per thread (4 tagged u32 each),
// one vmcnt(0), retry both on any tag miss. "=&v" early-clobber +
// sched_barrier(0) after waits. Per-u32 tags make 16B tearing harmless.
// Termination: a word cannot advance past tag t until this reader's WG
// publishes t+1 (parity double buffer). Overwrite safety: publishing tag t+1
// requires having observed tag t from ALL slices => all finished reading t-1.
// In-loop barriers are s_waitcnt lgkmcnt(0); s_barrier (LDS-only ordering);
// publish/out store-acks drain inside the next poll's vmcnt(0).
// hbuf MUST be 128 KB (earlier sessions hung: 64 KB aliased cstate over tags).
// Mode-A (same-XCD L2 exchange) abandoned: sc0 polls can cache stale clean
// lines (livelock / silent cross-replay corruption) without L2 inv/wb ops.
// Round-8 lesson: HIP predefines ushort4 -> use ushort4v.
// ---------------------------------------------------------------------------

typedef __attribute__((ext_vector_type(8))) short short8;
typedef __attribute__((ext_vector_type(4))) float float4v;
typedef __attribute__((ext_vector_type(4))) unsigned int uint4v;
typedef __attribute__((ext_vector_type(4))) unsigned short ushort4v;

#define TT   2048
#define BB   64
#define HH   256
#define TBH  ((size_t)33554432)   // T*B*H
#define BH   ((size_t)16384)      // B*H

// workspace layout (bytes)
#define WS_WT    0u          // 1 MB    bf16 WT[1024][512]
#define WS_BVEC  1048576u    // 4 KB    fp32 bias[1024]
#define WS_HBUF  1052672u    // 128 KB  u32 hbuf[4][2][16][256] tagged cols
#define WS_CST   1183744u    // 64 KB   fp32 cstate[64][256]
#define WS_G     1249280u    // Tc*64*1024*2  bf16 G2 [R/4][1024][4]

__device__ inline unsigned short f2bf(float x) {
    unsigned u = __float_as_uint(x);
    unsigned r = (u + 0x7FFFu + ((u >> 16) & 1u)) >> 16;
    return (unsigned short)r;
}
__device__ inline float bf2f(unsigned short x) {
    return __uint_as_float((unsigned)x << 16);
}
__device__ inline float sigmoidf_(float x) { return 1.0f / (1.0f + __expf(-x)); }
__device__ inline float tanhf_(float x) {
    float e = __expf(-2.0f * fabsf(x));
    float t = (1.0f - e) / (1.0f + e);
    return copysignf(t, x);
}

// LDS-only workgroup barrier: orders ds ops (hsm/gbuf) without draining
// vmcnt (publish/out store-acks stay in flight across the barrier).
__device__ inline void bar_lds() {
    asm volatile("s_waitcnt lgkmcnt(0)\n\ts_barrier" ::: "memory");
}

// ---------------------------------------------------------------------------
// Prep: WT[c][k] = W_gate(c/256)[k][c%256]  (bf16, k in [0,512)), bvec[c]=bias
// ---------------------------------------------------------------------------
__global__ void k_prep_w(const float* __restrict__ Wf, const float* __restrict__ Wi,
                         const float* __restrict__ Wg, const float* __restrict__ Wo,
                         const float* __restrict__ bf_, const float* __restrict__ bi_,
                         const float* __restrict__ bg_, const float* __restrict__ bo_,
                         unsigned short* __restrict__ WT, float* __restrict__ bvec)
{
    int c = blockIdx.x;            // 0..1023
    int gate = c >> 8, j = c & 255;
    const float* W  = (gate == 0) ? Wf : (gate == 1) ? Wi : (gate == 2) ? Wg : Wo;
    const float* bb = (gate == 0) ? bf_ : (gate == 1) ? bi_ : (gate == 2) ? bg_ : bo_;
    for (int k = threadIdx.x; k < 512; k += 256)
        WT[(size_t)c * 512 + k] = f2bf(W[(size_t)k * 256 + j]);
    if (threadIdx.x == 0) bvec[c] = bb[j];
}

__global__ void k_zero(unsigned int* __restrict__ hbuf, float* __restrict__ cst)
{
    int tid = blockIdx.x * blockDim.x + threadIdx.x;
    int nt = gridDim.x * blockDim.x;
    for (int i = tid; i < 32768; i += nt) hbuf[i] = 0u;  // 128 KB, tag 0 = h_{-1}=0
    for (int i = tid; i < 16384; i += nt) cst[i] = 0.f;  // 64 KB
}

// ---------------------------------------------------------------------------
// Phase 1: G2[r>>2][c][r&3] = bf16( sum_k X[r][k]*WT[c][k] + bvec[c] )
// 128x128 tile, 4 waves, BK=64, XOR-swizzled LDS, fp32->bf16 on the fly.
// ---------------------------------------------------------------------------
__global__ __launch_bounds__(256) void gemm_xw(
    const float* __restrict__ X,           // chunk base [R][256] fp32
    const unsigned short* __restrict__ WT, // [1024][512] bf16
    const float* __restrict__ bvec,
    unsigned short* __restrict__ G2)       // [R/4][1024][4] bf16 packed
{
    int col0 = blockIdx.x * 128;
    int row0 = blockIdx.y * 128;
    int tid = threadIdx.x, l = tid & 63, w = tid >> 6;
    int wr = w >> 1, wc = w & 1;

    __shared__ __align__(16) unsigned char asm_[16384];
    __shared__ __align__(16) unsigned char bsm_[16384];

    float4v acc[4][4];
#pragma unroll
    for (int i = 0; i < 4; ++i)
#pragma unroll
        for (int j = 0; j < 4; ++j) { acc[i][j][0] = 0.f; acc[i][j][1] = 0.f; acc[i][j][2] = 0.f; acc[i][j][3] = 0.f; }

    for (int kt = 0; kt < 4; ++kt) {
        // stage A (fp32 -> bf16): 128 rows x 64 k
        {
            int r = tid >> 1, seg = tid & 1;
            const float* src = X + (size_t)(row0 + r) * 256 + kt * 64 + seg * 32;
            short8 tmp[4];
#pragma unroll
            for (int v = 0; v < 4; ++v)
#pragma unroll
                for (int e = 0; e < 8; ++e) tmp[v][e] = (short)f2bf(src[v * 8 + e]);
            unsigned char* dst = asm_ + r * 128;
            int base = seg * 64, swz = (r & 7) << 4;
#pragma unroll
            for (int v = 0; v < 4; ++v)
                *(short8*)(dst + ((base + 16 * v) ^ swz)) = tmp[v];
        }
        // stage B (bf16 copy): 128 cols x 64 k
        {
            int c_ = tid >> 1, seg = tid & 1;
            const unsigned char* src = (const unsigned char*)WT + (size_t)(col0 + c_) * 1024 + kt * 128 + seg * 64;
            unsigned char* dst = bsm_ + c_ * 128;
            int base = seg * 64, swz = (c_ & 7) << 4;
#pragma unroll
            for (int v = 0; v < 4; ++v)
                *(short8*)(dst + ((base + 16 * v) ^ swz)) = *(const short8*)(src + 16 * v);
        }
        __syncthreads();
#pragma unroll
        for (int km = 0; km < 2; ++km) {
            short8 af[4], bfr[4];
            int kb = 16 * (l >> 4) + 64 * km, swz = (l & 7) << 4;
#pragma unroll
            for (int i = 0; i < 4; ++i)
                af[i] = *(const short8*)(asm_ + (wr * 64 + i * 16 + (l & 15)) * 128 + (kb ^ swz));
#pragma unroll
            for (int j = 0; j < 4; ++j)
                bfr[j] = *(const short8*)(bsm_ + (wc * 64 + j * 16 + (l & 15)) * 128 + (kb ^ swz));
#pragma unroll
            for (int i = 0; i < 4; ++i)
#pragma unroll
                for (int j = 0; j < 4; ++j)
                    acc[i][j] = __builtin_amdgcn_mfma_f32_16x16x32_bf16(af[i], bfr[j], acc[i][j], 0, 0, 0);
        }
        __syncthreads();
    }
    // epilogue: + bias, pack 4 row-values to bf16, one 8B store each
#pragma unroll
    for (int j = 0; j < 4; ++j) {
        int col = col0 + wc * 64 + j * 16 + (l & 15);
        float bias = bvec[col];
#pragma unroll
        for (int i = 0; i < 4; ++i) {
            int row = row0 + wr * 64 + i * 16 + (l >> 4) * 4;   // row % 4 == 0
            ushort4v v;
            v[0] = f2bf(acc[i][j][0] + bias);
            v[1] = f2bf(acc[i][j][1] + bias);
            v[2] = f2bf(acc[i][j][2] + bias);
            v[3] = f2bf(acc[i][j][3] + bias);
            *(ushort4v*)(G2 + ((size_t)(row >> 2) * 1024 + col) * 4) = v;
        }
    }
}

// ---------------------------------------------------------------------------
// Phase 2: persistent recurrent kernel for a chunk of Tc steps.
// Grid 64 blocks x 512 thr; g = wg&7 (>=4 -> exit), s = wg>>3.
// Wave w: gate = w&3, dh = w>>2 -> 16 cols; weights in 32 VGPRs/lane.
// __launch_bounds__(512, 1): 1 WG/CU grid -> give the allocator the full
// VGPR budget so bw[8] stays register-resident (no per-step remat).
// ---------------------------------------------------------------------------
__global__ __launch_bounds__(512, 1) void lstm_rec(
    const unsigned short* __restrict__ G2,  // [Tc*16][1024][4] bf16 packed
    const unsigned short* __restrict__ WT,  // [1024][512] bf16
    float* __restrict__ out,
    unsigned int* __restrict__ hbuf,        // [4][2][16][256] tagged cols
    float* __restrict__ cstate,             // [64][256] fp32
    int t0, int Tc)
{
    int wg = blockIdx.x;
    int g = wg & 7;
    if (g >= 4) return;
    int s = wg >> 3;                  // 0..7

    int tid = threadIdx.x, l = tid & 63, w = tid >> 6;
    int gate = w & 3, dh = w >> 2;
    int c_lane = gate * 256 + s * 32 + dh * 16 + (l & 15);

    __shared__ __align__(16) unsigned char hsm[8192];   // h tile [16][256] bf16, swizzled
    __shared__ float gbuf[4][16][32];                   // pre-activations

    // weights -> registers: k bytes [512,1024) of WT row c_lane
    short8 bw[8];
    {
        const unsigned char* wp_ = (const unsigned char*)WT + (size_t)c_lane * 1024 + 512 + 16 * (l >> 4);
#pragma unroll
        for (int kk = 0; kk < 8; ++kk) bw[kk] = *(const short8*)(wp_ + 64 * kk);
    }

    // per-thread combine/publish element: row b_ (0..15), col j_ (0..31)
    int b_ = tid >> 5, j_ = tid & 31;
    float creg = cstate[(size_t)(g * 16 + b_) * 256 + s * 32 + j_];

    // poll/staging mapping: row srow (0..15), 8-col block sblk (0..31)
    int srow = tid >> 5, sblk = tid & 31;
    unsigned char* hsm_dst = hsm + srow * 512 + ((sblk * 16) ^ ((srow & 7) << 4));

    for (int tl = 0; tl < Tc; ++tl) {
        int tg = t0 + tl;
        int par = tg & 1, rpar = par ^ 1;

        // G preload: ONE 8B packed load (4 row-values of c_lane), issued
        // before the poll; in flight during the poll RTT, drained by the
        // poll's vmcnt(0). Convert AFTER the poll (pinned below).
        ushort4v gv;
        {
            const unsigned short* Gp = G2 +
                (((size_t)((tl * 64 + g * 16) >> 2) + (l >> 4)) * 1024 + c_lane) * 4;
            gv = *(const ushort4v*)Gp;
        }
        // spin-read h_{tg-1}: 2 CONCURRENT dwordx4 sc1 (agent UC) loads,
        // one vmcnt(0) (also drains the G load + prior store-acks, all
        // overlapped with the load RTT); retry both on any tag miss.
        {
            const unsigned int* wp = hbuf + ((size_t)((g * 2 + rpar) * 16) + srow) * 256 + sblk * 8;
            unsigned want = (unsigned)tg;
            short8 hv;
            uint4v w0, w1;
            for (;;) {
                asm volatile("global_load_dwordx4 %0, %2, off sc1\n\t"
                             "global_load_dwordx4 %1, %3, off sc1\n\t"
                             "s_waitcnt vmcnt(0)"
                             : "=&v"(w0), "=&v"(w1)
                             : "v"(wp), "v"(wp + 4) : "memory");
                __builtin_amdgcn_sched_barrier(0);
                if (((w0[0] >> 16) == want) & ((w0[1] >> 16) == want) &
                    ((w0[2] >> 16) == want) & ((w0[3] >> 16) == want) &
                    ((w1[0] >> 16) == want) & ((w1[1] >> 16) == want) &
                    ((w1[2] >> 16) == want) & ((w1[3] >> 16) == want)) break;
            }
            hv[0] = (short)(w0[0] & 0xffffu);
            hv[1] = (short)(w0[1] & 0xffffu);
            hv[2] = (short)(w0[2] & 0xffffu);
            hv[3] = (short)(w0[3] & 0xffffu);
            hv[4] = (short)(w1[0] & 0xffffu);
            hv[5] = (short)(w1[1] & 0xffffu);
            hv[6] = (short)(w1[2] & 0xffffu);
            hv[7] = (short)(w1[3] & 0xffffu);
            *(short8*)hsm_dst = hv;
        }
        // pin gv consumption AFTER the poll (blocks MachineLICM hoisting the
        // convert + its waitcnt above the poll); poll's vmcnt(0) made gv valid.
        asm volatile("" : "+v"(gv));
        float4v acc;
        acc[0] = bf2f(gv[0]);
        acc[1] = bf2f(gv[1]);
        acc[2] = bf2f(gv[2]);
        acc[3] = bf2f(gv[3]);
        bar_lds();   // hsm writes visible; no vmcnt drain (stores stay in flight)
        // pre += h @ Wh(cols): two independent 4-MFMA chains
        {
            int row = l & 15;
            const unsigned char* ap = hsm + row * 512;
            int kb0 = 16 * (l >> 4), swz = (row & 7) << 4;
            short8 af[8];
#pragma unroll
            for (int kk = 0; kk < 8; ++kk) af[kk] = *(const short8*)(ap + ((kb0 + 64 * kk) ^ swz));
            float4v acc1 = {0.f, 0.f, 0.f, 0.f};
#pragma unroll
            for (int kk = 0; kk < 4; ++kk) {
                acc  = __builtin_amdgcn_mfma_f32_16x16x32_bf16(af[kk],     bw[kk],     acc,  0, 0, 0);
                acc1 = __builtin_amdgcn_mfma_f32_16x16x32_bf16(af[kk + 4], bw[kk + 4], acc1, 0, 0, 0);
            }
            acc[0] += acc1[0]; acc[1] += acc1[1]; acc[2] += acc1[2]; acc[3] += acc1[3];
        }
        // publish pre-activations to LDS
        {
            int r0 = (l >> 4) * 4, cc = dh * 16 + (l & 15);
            gbuf[gate][r0 + 0][cc] = acc[0];
            gbuf[gate][r0 + 1][cc] = acc[1];
            gbuf[gate][r0 + 2][cc] = acc[2];
            gbuf[gate][r0 + 3][cc] = acc[3];
        }
        bar_lds();   // gbuf writes visible
        // combine: all 512 threads, one (b_, j_) element each
        {
            float f  = sigmoidf_(gbuf[0][b_][j_]);
            float i  = sigmoidf_(gbuf[1][b_][j_]);
            float gg = tanhf_(gbuf[2][b_][j_]);
            float o  = sigmoidf_(gbuf[3][b_][j_]);
            creg = f * creg + i * gg;
            float h = o * tanhf_(creg);
            // tagged publish ASAP (relaxed, agent): tag = tg+1
            unsigned word = ((unsigned)(tg + 1) << 16) | (unsigned)f2bf(h);
            __hip_atomic_store(hbuf + ((size_t)((g * 2 + par) * 16) + b_) * 256 + s * 32 + j_,
                               word, __ATOMIC_RELAXED, __HIP_MEMORY_SCOPE_AGENT);
            size_t orow = (size_t)tg * 64 + g * 16 + b_;
            out[orow * 256 + s * 32 + j_] = h;
            if (tg == TT - 1) {
                out[TBH + (size_t)(g * 16 + b_) * 256 + s * 32 + j_] = h;
                out[TBH + BH + (size_t)(g * 16 + b_) * 256 + s * 32 + j_] = creg;
            }
        }
        bar_lds();   // protects hsm/gbuf reuse; publish/out store-acks drain
                     // in background (next poll's vmcnt(0) picks them up).
    }
    cstate[(size_t)(g * 16 + b_) * 256 + s * 32 + j_] = creg;
}

// ---------------------------------------------------------------------------
extern "C" void kernel_launch(void* const* d_in, const int* in_sizes, int n_in,
                              void* d_out, int out_size, void* d_ws, size_t ws_size,
                              hipStream_t stream)
{
    (void)in_sizes; (void)n_in; (void)out_size;
    const float* X   = (const float*)d_in[0];
    const float* Wf  = (const float*)d_in[1];
    const float* bf_ = (const float*)d_in[2];
    const float* Wi  = (const float*)d_in[3];
    const float* bi_ = (const float*)d_in[4];
    const float* Wg  = (const float*)d_in[5];
    const float* bg_ = (const float*)d_in[6];
    const float* Wo  = (const float*)d_in[7];
    const float* bo_ = (const float*)d_in[8];
    float* out = (float*)d_out;
    unsigned char* ws = (unsigned char*)d_ws;

    unsigned short* WT   = (unsigned short*)(ws + WS_WT);
    float*          bvec = (float*)(ws + WS_BVEC);
    unsigned int*   hbuf = (unsigned int*)(ws + WS_HBUF);
    float*          cst  = (float*)(ws + WS_CST);
    unsigned short* G2   = (unsigned short*)(ws + WS_G);

    // Tc capped at 512: bf16 G chunk = 64 MB, L3-resident between gemm
    // (writer) and lstm_rec (reader).
    size_t avail = ws_size > WS_G ? ws_size - WS_G : 0;
    int Tc = 8;
    const int cands[7] = {512, 256, 128, 64, 32, 16, 8};
    for (int i = 0; i < 7; ++i) {
        if ((size_t)cands[i] * 64 * 1024 * 2 <= avail) { Tc = cands[i]; break; }
    }

    k_prep_w<<<1024, 256, 0, stream>>>(Wf, Wi, Wg, Wo, bf_, bi_, bg_, bo_, WT, bvec);
    k_zero<<<64, 256, 0, stream>>>(hbuf, cst);

    for (int t0 = 0; t0 < TT; t0 += Tc) {
        int R = Tc * 64;
        gemm_xw<<<dim3(8, R / 128), 256, 0, stream>>>(X + (size_t)t0 * 64 * 256, WT, bvec, G2);
        lstm_rec<<<64, 512, 0, stream>>>(G2, WT, out, hbuf, cst, t0, Tc);
    }
}